// Round 9
// baseline (128.487 us; speedup 1.0000x reference)
//
#include <hip/hip_runtime.h>

// TopDownHTMM fused forward, v5 (resubmit — round 8 was an acquisition
// timeout; this kernel has never run).
// v4 post-mortem: spill eliminated (WRITE 67MB->16KB) but dur unchanged at
// ~51us -> kernel is latency-bound on the ~27 barrier-phase structure, not
// on memory. v5: two tree levels per barrier phase (bit-identical math,
// intermediates stay in registers), 27 -> 17 barriers, 3-7 nodes of ILP per
// thread per phase; row-major b128-friendly LDS dot products.

#define NTREES 64
#define DEPTH  10
#define C      8
#define M      32
#define G      8
#define NPT    2047
#define PAD    9            // floats per node slot (odd -> conflict-light)
#define BLOCK  512
#define LNODES 1023         // nodes of levels 0..9

__device__ __forceinline__ float frcp(float v) { return __builtin_amdgcn_rcpf(v); }

__device__ __forceinline__ void ldsRead(const float* buf, int node, float (&v)[C]) {
    #pragma unroll
    for (int i = 0; i < C; ++i) v[i] = buf[node*PAD + i];
}
__device__ __forceinline__ void ldsWrite(float* buf, int node, const float (&v)[C]) {
    #pragma unroll
    for (int i = 0; i < C; ++i) buf[node*PAD + i] = v[i];
}

// o = sA * p (o_i = sum_j sA[i][j] p_j), row-major LDS access
__device__ __forceinline__ void matvec(const float (&sA)[C][C], const float (&p)[C],
                                       float (&o)[C]) {
    #pragma unroll
    for (int i = 0; i < C; ++i) {
        float a = 0.f;
        #pragma unroll
        for (int j = 0; j < C; ++j) a += sA[i][j] * p[j];
        o[i] = a;
    }
}

// Upward (beta) step for one node: children ratios rr1,rr2; prior pr; symbol xu.
// outv = ratio (emit*prod/Z), or for ROOT: eps_root = pr*emit*prod/Z.
// Accumulation over i ascending (row-major i-outer) — matches reference einsum.
template<bool ROOT>
__device__ __forceinline__ void up_node(const float (&sA)[C][C], const float (&sB)[C][M],
                                        const float (&rr1)[C], const float (&rr2)[C],
                                        const float (&pr)[C], int xu, float (&outv)[C])
{
    float a1[C], a2[C];
    #pragma unroll
    for (int j = 0; j < C; ++j) { a1[j] = 0.f; a2[j] = 0.f; }
    #pragma unroll
    for (int i = 0; i < C; ++i) {
        #pragma unroll
        for (int j = 0; j < C; ++j) {
            const float aij = sA[i][j];
            a1[j] += aij * rr1[i];
            a2[j] += aij * rr2[i];
        }
    }
    float ep[C]; float Z = 0.f;
    #pragma unroll
    for (int j = 0; j < C; ++j) {
        ep[j] = sB[j][xu] * (a1[j] * a2[j]);
        Z += pr[j] * ep[j];
    }
    const float iz = frcp(Z);
    #pragma unroll
    for (int j = 0; j < C; ++j) outv[j] = ROOT ? pr[j]*ep[j]*iz : ep[j]*iz;
}

// Downward (eps) step: ratio r, parent eps epa, symbol xv. Returns lik term;
// if WEPS writes node eps to eout.
template<bool WEPS>
__device__ __forceinline__ float child_node(const float (&sA)[C][C],
                                            const float (&sAL)[C][C],
                                            const float (&lgB)[C][M],
                                            const float (&r)[C],
                                            const float (&epa)[C],
                                            int xv,
                                            float (&eout)[C])
{
    float tb[C];
    #pragma unroll
    for (int j = 0; j < C; ++j) tb[j] = 0.f;
    #pragma unroll
    for (int i = 0; i < C; ++i) {
        #pragma unroll
        for (int j = 0; j < C; ++j) tb[j] += sA[i][j] * r[i];
    }
    float f[C];
    #pragma unroll
    for (int j = 0; j < C; ++j) f[j] = epa[j] * frcp(tb[j]);
    float S = 0.f, likA = 0.f, num[C];
    #pragma unroll
    for (int i = 0; i < C; ++i) {
        float a = 0.f, la = 0.f;
        #pragma unroll
        for (int j = 0; j < C; ++j) { a += sA[i][j] * f[j]; la += sAL[i][j] * f[j]; }
        num[i] = r[i] * a;
        S     += num[i];
        likA  += r[i] * la;
    }
    const float invS = frcp(S);
    float likE = 0.f;
    #pragma unroll
    for (int i = 0; i < C; ++i) {
        const float e2 = num[i] * invS;
        if constexpr (WEPS) eout[i] = e2;
        likE += e2 * lgB[i][xv];
    }
    return likA + likE;
}

__global__ __launch_bounds__(BLOCK, 2)
void htmm_kernel(const float* __restrict__ A,   // (C,C,G)
                 const float* __restrict__ B,   // (C,M,G)
                 const float* __restrict__ Pi,  // (C,G)
                 const int*   __restrict__ x,   // (DIM,)
                 float* __restrict__ out)       // (NTREES,G)
{
    __shared__ float buf[LNODES * PAD];         // 36,828 B
    __shared__ float sA[C][C], sAL[C][C];       // softmax_i A ; sA*log(sA)
    __shared__ float sB[C][M], lgB[C][M];
    __shared__ float spi[C],  lgpi[C];
    __shared__ float bls[C];                    // per-row logsumexp of B
    __shared__ float red8[BLOCK / 64];

    const int b   = blockIdx.x;
    const int t   = b >> 3;
    const int g   = b & 7;
    const int tid = threadIdx.x;
    const int base = t * NPT;

    // Subtree symbol loads issued early (hide HBM latency under prep/pass1).
    const int s  = 511 + tid;                    // owned level-9 node
    const int xs = x[base + s];
    const int x1 = x[base + 2*s + 1];
    const int x2 = x[base + 2*s + 2];

    // ---------------- phase 1: row stats ----------------
    if (tid < C) {                               // A column j: softmax over i
        const int j = tid;
        float w[C]; float mx = -1e30f;
        #pragma unroll
        for (int i = 0; i < C; ++i) { w[i] = A[(i*C + j)*G + g]; mx = fmaxf(mx, w[i]); }
        float s0 = 0.f; float e[C];
        #pragma unroll
        for (int i = 0; i < C; ++i) { e[i] = expf(w[i] - mx); s0 += e[i]; }
        const float inv = 1.f / s0, ls = logf(s0);
        #pragma unroll
        for (int i = 0; i < C; ++i) {
            const float sm = e[i] * inv;
            sA[i][j]  = sm;
            sAL[i][j] = sm * ((w[i] - mx) - ls);
        }
    } else if (tid == 8) {                       // Pi softmax
        float w[C]; float mx = -1e30f;
        #pragma unroll
        for (int c = 0; c < C; ++c) { w[c] = Pi[c*G + g]; mx = fmaxf(mx, w[c]); }
        float s0 = 0.f; float e[C];
        #pragma unroll
        for (int c = 0; c < C; ++c) { e[c] = expf(w[c] - mx); s0 += e[c]; }
        const float inv = 1.f / s0, ls = logf(s0);
        #pragma unroll
        for (int c = 0; c < C; ++c) { spi[c] = e[c]*inv; lgpi[c] = (w[c]-mx) - ls; }
    } else if (tid >= 64 && tid < 64 + C) {      // B row c: logsumexp
        const int c = tid - 64;
        float mx = -1e30f;
        #pragma unroll
        for (int m = 0; m < M; ++m) mx = fmaxf(mx, B[(c*M + m)*G + g]);
        float s0 = 0.f;
        #pragma unroll
        for (int m = 0; m < M; ++m) s0 += expf(B[(c*M + m)*G + g] - mx);
        bls[c] = mx + logf(s0);
    }
    __syncthreads();

    // ---------------- phase 2: B softmax wide + root prior ----------------
    if (tid < C * M) {                           // 256 threads: one (c,m) each
        const int c = tid >> 5, m = tid & 31;
        const float d0 = B[(c*M + m)*G + g] - bls[c];
        lgB[c][m] = d0;
        sB[c][m]  = expf(d0);
    }
    if (tid == 320) {
        #pragma unroll
        for (int i = 0; i < C; ++i) buf[i] = spi[i];
    }
    __syncthreads();

    // ---------------- pass 1: prior, two levels per phase ----------------
    // parent level p computes children (p+1) and grandchildren (p+2).
    // Both children share one prior; all 4 grandchildren share one prior.
    #pragma unroll 1
    for (int p = 0; p < 8; p += 2) {
        if (tid < (1 << p)) {
            const int u = (1 << p) - 1 + tid;
            float pp[C], c[C], gk[C];
            ldsRead(buf, u, pp);
            matvec(sA, pp, c);                   // prior of both children
            matvec(sA, c,  gk);                  // prior of all 4 grandchildren
            const int cb = 2*u + 1, gb = 4*u + 3;
            ldsWrite(buf, cb,   c);  ldsWrite(buf, cb+1, c);
            ldsWrite(buf, gb,   gk); ldsWrite(buf, gb+1, gk);
            ldsWrite(buf, gb+2, gk); ldsWrite(buf, gb+3, gk);
        }
        __syncthreads();
    }

    // ---------------- pass 1+2: subtree (levels 9,10) in registers ----------------
    float ps[C], pc[C];                          // prior of s; prior of both leaves
    {
        const int pas = 255 + (tid >> 1);        // parent at level 8
        float pp[C];
        ldsRead(buf, pas, pp);
        matvec(sA, pp, ps);
        matvec(sA, ps, pc);
    }
    float rs[C], r1[C], r2[C];
    {
        float Z1 = 0.f, Z2 = 0.f;
        #pragma unroll
        for (int i = 0; i < C; ++i) {
            r1[i] = sB[i][x1]; Z1 += pc[i] * r1[i];
            r2[i] = sB[i][x2]; Z2 += pc[i] * r2[i];
        }
        const float i1 = frcp(Z1), i2 = frcp(Z2);
        #pragma unroll
        for (int i = 0; i < C; ++i) { r1[i] *= i1; r2[i] *= i2; }
        up_node<false>(sA, sB, r1, r2, ps, xs, rs);
        ldsWrite(buf, s, rs);
    }
    __syncthreads();

    // ---------------- pass 2: ratios, two levels per phase ----------------
    // thread at level p computes ratios of its 2 children (p+1) then its own.
    #pragma unroll 1
    for (int p = 7; p >= 1; p -= 2) {
        if (tid < (1 << p)) {
            const int u  = (1 << p) - 1 + tid;
            const int c1 = 2*u + 1, c2 = 2*u + 2;
            float rc1[C], rc2[C];
            {
                float ra[C], rb[C], pr[C];
                ldsRead(buf, 2*c1+1, ra); ldsRead(buf, 2*c1+2, rb); ldsRead(buf, c1, pr);
                up_node<false>(sA, sB, ra, rb, pr, x[base + c1], rc1);
            }
            {
                float ra[C], rb[C], pr[C];
                ldsRead(buf, 2*c2+1, ra); ldsRead(buf, 2*c2+2, rb); ldsRead(buf, c2, pr);
                up_node<false>(sA, sB, ra, rb, pr, x[base + c2], rc2);
            }
            float pr[C], ru[C];
            ldsRead(buf, u, pr);
            up_node<false>(sA, sB, rc1, rc2, pr, x[base + u], ru);
            ldsWrite(buf, c1, rc1); ldsWrite(buf, c2, rc2); ldsWrite(buf, u, ru);
        }
        __syncthreads();
    }
    if (tid == 0) {                              // root: eps_root
        float ra[C], rb[C], pr[C], er[C];
        ldsRead(buf, 1, ra); ldsRead(buf, 2, rb); ldsRead(buf, 0, pr);
        up_node<true>(sA, sB, ra, rb, pr, x[base], er);
        ldsWrite(buf, 0, er);
    }
    __syncthreads();

    // ---------------- pass 3: eps + likelihood, two levels per phase ----------------
    float lik = 0.f;
    if (tid == 0) {                              // root lik: eps*(logPi + log emit)
        const int xr = x[base];
        float er[C];
        ldsRead(buf, 0, er);
        #pragma unroll
        for (int c = 0; c < C; ++c) lik += er[c] * (lgpi[c] + lgB[c][xr]);
    }
    #pragma unroll 1
    for (int q = 1; q <= 7; q += 2) {
        if (tid < (1 << q)) {
            const int v = (1 << q) - 1 + tid, pa = (v - 1) >> 1;
            float epa[C], r[C], ev[C];
            ldsRead(buf, pa, epa);
            ldsRead(buf, v, r);
            lik += child_node<true>(sA, sAL, lgB, r, epa, x[base + v], ev);
            ldsWrite(buf, v, ev);
            const int c1 = 2*v + 1;
            {
                float rc[C], ec[C];
                ldsRead(buf, c1, rc);
                lik += child_node<true>(sA, sAL, lgB, rc, ev, x[base + c1], ec);
                ldsWrite(buf, c1, ec);
            }
            {
                float rc[C], ec[C];
                ldsRead(buf, c1+1, rc);
                lik += child_node<true>(sA, sAL, lgB, rc, ev, x[base + c1 + 1], ec);
                ldsWrite(buf, c1+1, ec);
            }
        }
        __syncthreads();
    }
    {   // subtree: node s then its two leaves, all in registers
        const int pas = 255 + (tid >> 1);
        float epa[C], es[C], dummy[C];
        ldsRead(buf, pas, epa);
        lik += child_node<true >(sA, sAL, lgB, rs, epa, xs, es);
        lik += child_node<false>(sA, sAL, lgB, r1, es,  x1, dummy);
        lik += child_node<false>(sA, sAL, lgB, r2, es,  x2, dummy);
    }

    // ---------------- reduce lik over block ----------------
    #pragma unroll
    for (int off = 32; off; off >>= 1) lik += __shfl_xor(lik, off, 64);
    if ((tid & 63) == 0) red8[tid >> 6] = lik;
    __syncthreads();
    if (tid == 0) {
        float acc = 0.f;
        #pragma unroll
        for (int w = 0; w < BLOCK/64; ++w) acc += red8[w];
        out[t*G + g] = -acc;
    }
}

extern "C" void kernel_launch(void* const* d_in, const int* in_sizes, int n_in,
                              void* d_out, int out_size, void* d_ws, size_t ws_size,
                              hipStream_t stream) {
    const float* A  = (const float*)d_in[0];
    const float* B  = (const float*)d_in[1];
    const float* Pi = (const float*)d_in[2];
    const int*   x  = (const int*)d_in[3];
    float* out = (float*)d_out;
    htmm_kernel<<<NTREES * G, BLOCK, 0, stream>>>(A, B, Pi, x, out);
}

// Round 10
// 123.946 us; speedup vs baseline: 1.0366x; 1.0366x over previous
//
#include <hip/hip_runtime.h>

// TopDownHTMM fused forward, v6.
// v5 post-mortem: 2-levels/phase tripled live registers -> spill returned
// (20 MB WRITE) -> regression. New structure:
//  (a) prior[node] depends only on DEPTH (prior=sA^d*pi): pass 1 collapses
//      from 1023 matvecs/block to 10.
//  (b) 8 waves/block, each owns one level-3 subtree (255 nodes, levels 3-10).
//      Within a wave: no barriers (wave-synchronous LDS, compiler fences).
//      Only the 7 top nodes (levels 0-2) use block barriers: 9 total vs 27.
//  One node-op live per iteration -> ~50 VGPR peak, no spill at (512,2).

#define NTREES 64
#define C      8
#define M      32
#define G      8
#define NPT    2047
#define PAD    9            // slot stride 9 floats: 2-lane bank aliasing only
#define BLOCK  512
#define SUBN   255          // nodes per wave subtree (tree levels 3..10)

__device__ __forceinline__ float frcp(float v) { return __builtin_amdgcn_rcpf(v); }
__device__ __forceinline__ void cfence() { asm volatile("" ::: "memory"); }

__device__ __forceinline__ void ldsRead(const float* p, int slot, float (&v)[C]) {
    #pragma unroll
    for (int i = 0; i < C; ++i) v[i] = p[slot*PAD + i];
}
__device__ __forceinline__ void ldsWrite(float* p, int slot, const float (&v)[C]) {
    #pragma unroll
    for (int i = 0; i < C; ++i) p[slot*PAD + i] = v[i];
}

// Upward (beta) step: children ratios rr1,rr2; prior pr; symbol xu.
// outv = ratio (emit*prod/Z); ROOT: eps_root = pr*emit*prod/Z.
template<bool ROOT>
__device__ __forceinline__ void up_node(const float (&sA)[C][C], const float (&sB)[C][M],
                                        const float (&rr1)[C], const float (&rr2)[C],
                                        const float (&pr)[C], int xu, float (&outv)[C])
{
    float a1[C], a2[C];
    #pragma unroll
    for (int j = 0; j < C; ++j) { a1[j] = 0.f; a2[j] = 0.f; }
    #pragma unroll
    for (int i = 0; i < C; ++i) {
        #pragma unroll
        for (int j = 0; j < C; ++j) {
            const float aij = sA[i][j];
            a1[j] += aij * rr1[i];
            a2[j] += aij * rr2[i];
        }
    }
    float ep[C]; float Z = 0.f;
    #pragma unroll
    for (int j = 0; j < C; ++j) {
        ep[j] = sB[j][xu] * (a1[j] * a2[j]);
        Z += pr[j] * ep[j];
    }
    const float iz = frcp(Z);
    #pragma unroll
    for (int j = 0; j < C; ++j) outv[j] = ROOT ? pr[j]*ep[j]*iz : ep[j]*iz;
}

// Downward (eps) step: ratio r, parent eps epa, symbol xv -> lik term (+eps out).
template<bool WEPS>
__device__ __forceinline__ float child_node(const float (&sA)[C][C],
                                            const float (&sAL)[C][C],
                                            const float (&lgB)[C][M],
                                            const float (&r)[C],
                                            const float (&epa)[C],
                                            int xv,
                                            float (&eout)[C])
{
    float tb[C];
    #pragma unroll
    for (int j = 0; j < C; ++j) tb[j] = 0.f;
    #pragma unroll
    for (int i = 0; i < C; ++i) {
        #pragma unroll
        for (int j = 0; j < C; ++j) tb[j] += sA[i][j] * r[i];
    }
    float f[C];
    #pragma unroll
    for (int j = 0; j < C; ++j) f[j] = epa[j] * frcp(tb[j]);
    float S = 0.f, likA = 0.f, num[C];
    #pragma unroll
    for (int i = 0; i < C; ++i) {
        float a = 0.f, la = 0.f;
        #pragma unroll
        for (int j = 0; j < C; ++j) { a += sA[i][j] * f[j]; la += sAL[i][j] * f[j]; }
        num[i] = r[i] * a;
        S     += num[i];
        likA  += r[i] * la;
    }
    const float invS = frcp(S);
    float likE = 0.f;
    #pragma unroll
    for (int i = 0; i < C; ++i) {
        const float e2 = num[i] * invS;
        if constexpr (WEPS) eout[i] = e2;
        likE += e2 * lgB[i][xv];
    }
    return likA + likE;
}

__global__ __launch_bounds__(BLOCK, 2)
void htmm_kernel(const float* __restrict__ A,   // (C,C,G)
                 const float* __restrict__ B,   // (C,M,G)
                 const float* __restrict__ Pi,  // (C,G)
                 const int*   __restrict__ x,   // (DIM,)
                 float* __restrict__ out)       // (NTREES,G)
{
    __shared__ float buf[8 * SUBN * PAD];       // 73,440 B: 8 subtrees x 255 slots
    __shared__ float top[7 * PAD];              // levels 0..2 (7 nodes)
    __shared__ float sA[C][C], sAL[C][C];
    __shared__ float sB[C][M], lgB[C][M];
    __shared__ float pri[11][C];                // prior per depth d=0..10
    __shared__ float lgpi[C];
    __shared__ float bls[C];
    __shared__ float red8[8];

    const int b    = blockIdx.x;
    const int t    = b >> 3;
    const int g    = b & 7;
    const int tid  = threadIdx.x;
    const int w    = tid >> 6;                   // wave = subtree id (level-3 node)
    const int lane = tid & 63;
    const int base = t * NPT;
    const int sbase = w * SUBN;                  // this wave's slot base

    // ---------------- phase 1: parameter softmax stats ----------------
    if (tid < C) {                               // A column j: softmax over i
        const int j = tid;
        float wv[C]; float mx = -1e30f;
        #pragma unroll
        for (int i = 0; i < C; ++i) { wv[i] = A[(i*C + j)*G + g]; mx = fmaxf(mx, wv[i]); }
        float s0 = 0.f; float e[C];
        #pragma unroll
        for (int i = 0; i < C; ++i) { e[i] = expf(wv[i] - mx); s0 += e[i]; }
        const float inv = 1.f / s0, ls = logf(s0);
        #pragma unroll
        for (int i = 0; i < C; ++i) {
            const float sm = e[i] * inv;
            sA[i][j]  = sm;
            sAL[i][j] = sm * ((wv[i] - mx) - ls);
        }
    } else if (tid == 8) {                       // Pi softmax -> pri[0], lgpi
        float wv[C]; float mx = -1e30f;
        #pragma unroll
        for (int c = 0; c < C; ++c) { wv[c] = Pi[c*G + g]; mx = fmaxf(mx, wv[c]); }
        float s0 = 0.f; float e[C];
        #pragma unroll
        for (int c = 0; c < C; ++c) { e[c] = expf(wv[c] - mx); s0 += e[c]; }
        const float inv = 1.f / s0, ls = logf(s0);
        #pragma unroll
        for (int c = 0; c < C; ++c) { pri[0][c] = e[c]*inv; lgpi[c] = (wv[c]-mx) - ls; }
    } else if (tid >= 64 && tid < 64 + C) {      // B row c: logsumexp
        const int c = tid - 64;
        float mx = -1e30f;
        #pragma unroll
        for (int m = 0; m < M; ++m) mx = fmaxf(mx, B[(c*M + m)*G + g]);
        float s0 = 0.f;
        #pragma unroll
        for (int m = 0; m < M; ++m) s0 += expf(B[(c*M + m)*G + g] - mx);
        bls[c] = mx + logf(s0);
    }
    __syncthreads();

    // ---------------- phase 2: B softmax wide + depth-prior chain ----------------
    if (tid < C * M) {                           // one (c,m) per thread
        const int c = tid >> 5, m = tid & 31;
        const float d0 = B[(c*M + m)*G + g] - bls[c];
        lgB[c][m] = d0;
        sB[c][m]  = expf(d0);
    }
    if (tid == 256) {                            // pri[d] = sA^d * pi, d=1..10
        float p[C], np[C];
        #pragma unroll
        for (int c = 0; c < C; ++c) p[c] = pri[0][c];
        #pragma unroll 1
        for (int d = 1; d <= 10; ++d) {
            #pragma unroll
            for (int i = 0; i < C; ++i) {
                float a = 0.f;
                #pragma unroll
                for (int j = 0; j < C; ++j) a += sA[i][j] * p[j];
                np[i] = a;
            }
            #pragma unroll
            for (int c = 0; c < C; ++c) { pri[d][c] = np[c]; p[c] = np[c]; }
        }
    }
    __syncthreads();

    // ============ pass 2 (up): per-wave subtree, NO barriers ============
    // leaves: tree level 10, 128 per subtree (2 iterations of 64 lanes)
    int xleaf0, xleaf1;
    {
        const int i0 = lane, q0 = 127 + i0;
        const int n0 = 1023 + w*128 + i0;
        xleaf0 = x[base + n0];
        float rr[C]; float Z = 0.f;
        #pragma unroll
        for (int c = 0; c < C; ++c) { rr[c] = sB[c][xleaf0]; Z += pri[10][c] * rr[c]; }
        const float iz = frcp(Z);
        #pragma unroll
        for (int c = 0; c < C; ++c) buf[(sbase+q0)*PAD + c] = rr[c] * iz;

        const int i1 = 64 + lane, q1 = 127 + i1;
        xleaf1 = x[base + n0 + 64];
        float rr2[C]; float Z2 = 0.f;
        #pragma unroll
        for (int c = 0; c < C; ++c) { rr2[c] = sB[c][xleaf1]; Z2 += pri[10][c] * rr2[c]; }
        const float iz2 = frcp(Z2);
        #pragma unroll
        for (int c = 0; c < C; ++c) buf[(sbase+q1)*PAD + c] = rr2[c] * iz2;
    }
    cfence();

    int xup[7];                                  // symbol per level (static idx)
    #pragma unroll
    for (int lam = 6; lam >= 0; --lam) {
        const int sz = 1 << lam;
        if (lane < sz) {
            const int q  = sz - 1 + lane;
            const int n  = ((1 << (3 + lam)) - 1) + w*sz + lane;
            const int xv = x[base + n];
            xup[lam] = xv;
            float ra[C], rb[C], pr[C], ro[C];
            ldsRead(buf, sbase + 2*q + 1, ra);
            ldsRead(buf, sbase + 2*q + 2, rb);
            #pragma unroll
            for (int c = 0; c < C; ++c) pr[c] = pri[3 + lam][c];
            up_node<false>(sA, sB, ra, rb, pr, xv, ro);
            ldsWrite(buf, sbase + q, ro);
        }
        cfence();
    }
    __syncthreads();

    // ============ top: levels 0..2 (7 nodes), short barrier phases ============
    float lik = 0.f;
    if (tid < 4) {                               // level-2 up (children = subtree roots)
        float ra[C], rb[C], pr[C], ro[C];
        ldsRead(buf, (2*tid)*SUBN,     ra);
        ldsRead(buf, (2*tid + 1)*SUBN, rb);
        #pragma unroll
        for (int c = 0; c < C; ++c) pr[c] = pri[2][c];
        up_node<false>(sA, sB, ra, rb, pr, x[base + 3 + tid], ro);
        ldsWrite(top, 3 + tid, ro);
    }
    __syncthreads();
    if (tid < 2) {                               // level-1 up
        float ra[C], rb[C], pr[C], ro[C];
        ldsRead(top, 3 + 2*tid, ra);
        ldsRead(top, 4 + 2*tid, rb);
        #pragma unroll
        for (int c = 0; c < C; ++c) pr[c] = pri[1][c];
        up_node<false>(sA, sB, ra, rb, pr, x[base + 1 + tid], ro);
        ldsWrite(top, 1 + tid, ro);
    }
    __syncthreads();
    if (tid == 0) {                              // root eps + root lik
        float ra[C], rb[C], pr[C], er[C];
        ldsRead(top, 1, ra);
        ldsRead(top, 2, rb);
        #pragma unroll
        for (int c = 0; c < C; ++c) pr[c] = pri[0][c];
        const int xr = x[base];
        up_node<true>(sA, sB, ra, rb, pr, xr, er);
        #pragma unroll
        for (int c = 0; c < C; ++c) lik += er[c] * (lgpi[c] + lgB[c][xr]);
        ldsWrite(top, 0, er);
    }
    __syncthreads();
    if (tid < 2) {                               // level-1 eps + lik
        float r[C], epa[C], eo[C];
        ldsRead(top, 1 + tid, r);
        ldsRead(top, 0, epa);
        lik += child_node<true>(sA, sAL, lgB, r, epa, x[base + 1 + tid], eo);
        ldsWrite(top, 1 + tid, eo);
    }
    __syncthreads();
    if (tid < 4) {                               // level-2 eps + lik
        float r[C], epa[C], eo[C];
        ldsRead(top, 3 + tid, r);
        ldsRead(top, 1 + (tid >> 1), epa);
        lik += child_node<true>(sA, sAL, lgB, r, epa, x[base + 3 + tid], eo);
        ldsWrite(top, 3 + tid, eo);
    }
    __syncthreads();

    // ============ pass 3 (down): per-wave subtree, NO barriers ============
    if (lane == 0) {                             // subtree root (tree node 7+w)
        float r[C], epa[C], eo[C];
        ldsRead(buf, sbase, r);
        ldsRead(top, 3 + (w >> 1), epa);
        lik += child_node<true>(sA, sAL, lgB, r, epa, xup[0], eo);
        ldsWrite(buf, sbase, eo);
    }
    cfence();
    #pragma unroll
    for (int lam = 1; lam <= 6; ++lam) {
        const int sz = 1 << lam;
        if (lane < sz) {
            const int q  = sz - 1 + lane;
            const int pa = (q - 1) >> 1;
            float r[C], epa[C], eo[C];
            ldsRead(buf, sbase + q,  r);
            ldsRead(buf, sbase + pa, epa);
            lik += child_node<true>(sA, sAL, lgB, r, epa, xup[lam], eo);
            ldsWrite(buf, sbase + q, eo);
        }
        cfence();
    }
    {   // leaves: 2 iterations, eps not stored
        float r[C], epa[C], dummy[C];
        const int q0 = 127 + lane, pa0 = (q0 - 1) >> 1;
        ldsRead(buf, sbase + q0,  r);
        ldsRead(buf, sbase + pa0, epa);
        lik += child_node<false>(sA, sAL, lgB, r, epa, xleaf0, dummy);
        const int q1 = 191 + lane, pa1 = (q1 - 1) >> 1;
        ldsRead(buf, sbase + q1,  r);
        ldsRead(buf, sbase + pa1, epa);
        lik += child_node<false>(sA, sAL, lgB, r, epa, xleaf1, dummy);
    }

    // ---------------- block reduction ----------------
    #pragma unroll
    for (int off = 32; off; off >>= 1) lik += __shfl_xor(lik, off, 64);
    if (lane == 0) red8[w] = lik;
    __syncthreads();
    if (tid == 0) {
        float acc = 0.f;
        #pragma unroll
        for (int k = 0; k < 8; ++k) acc += red8[k];
        out[t*G + g] = -acc;
    }
}

extern "C" void kernel_launch(void* const* d_in, const int* in_sizes, int n_in,
                              void* d_out, int out_size, void* d_ws, size_t ws_size,
                              hipStream_t stream) {
    const float* A  = (const float*)d_in[0];
    const float* B  = (const float*)d_in[1];
    const float* Pi = (const float*)d_in[2];
    const int*   x  = (const int*)d_in[3];
    float* out = (float*)d_out;
    htmm_kernel<<<NTREES * G, BLOCK, 0, stream>>>(A, B, Pi, x, out);
}